// Round 1
// 96.740 us; speedup vs baseline: 1.0265x; 1.0265x over previous
//
#include <hip/hip_runtime.h>
#include <hip/hip_fp16.h>

// Deformable conv B=4 C=64 H=W=128 O=64 3x3 s1 p1 d1, DG=1.
// v9 = v8 + 2-ho-row blocks: each block now computes a 64(o) x 64(n=2 rows x 32 wo)
// output tile. Same 16x48 fp16-octet LDS window covers both rows (margin ±6 rows,
// >5 sigma; exact global fallback for the ~1e-7 tail). Halves barrier count,
// window-stage traffic, and wt refetch per output; 1024 blocks = exactly one
// 4-block/CU occupancy round. v8 analysis: latency/barrier-bound, not pipe-bound.

#define B_  4
#define C_  64
#define H_  128
#define W_  128
#define O_  64
#define HO_ 128
#define WO_ 128
#define NCHUNK 8
#define NGW 12            // weight K-groups per chunk: 9 real taps + 3 zero
#define KSTEPS 3          // NGW*8 / 32
#define NT_ 32            // wo tile per block
#define NROW 2            // ho rows per block
#define NCOL 64           // NROW * NT_  (MFMA n dimension)
#define NTASK (9 * NCOL)  // 576 sampling tasks per chunk
#define SG  10            // sS groups per buffer: 9 taps + 1 zero pad
#define SBUF (SG * NCOL * 8)  // halves per buffer (5120 = 10 KB)
#define TR  16            // tile rows    (y in [ho-6, ho+10))
#define TC  48            // tile cols    (x in [woB-8, woB+40))
#define TSLOTS (TR * TC)  // 768 positions x 16 B = 12 KB

typedef _Float16 half8 __attribute__((ext_vector_type(8)));
typedef __attribute__((ext_vector_type(4))) float f32x4;

union H8 { float4 v; __half2 h2[4]; half8 v8; };

// Merged prep: blocks [0,2048) transpose+cvt x -> xt fp16 [B][CH=8][H][W][8ch];
// blocks [2048,2072) build wt fp16 [(ch*12+g)*64+o]*8+e  (g<9: tap g, else 0).
__global__ __launch_bounds__(256)
void prep(const float* __restrict__ x, const float* __restrict__ w,
          __half* __restrict__ xt, __half* __restrict__ wt) {
    const int tid = threadIdx.x;
    if (blockIdx.x < 2048) {
        int t = blockIdx.x * 256 + tid;          // (b,ch,y,x)
        int xc = t & 127;
        int y  = (t >> 7) & 127;
        int ch = (t >> 14) & 7;
        int b  = t >> 17;
        const float* xp = x + (((size_t)(b * C_ + ch * 8) * H_) + y) * W_ + xc;
        union { __half h[8]; float4 v; } pk;
#pragma unroll
        for (int e = 0; e < 8; ++e) pk.h[e] = __float2half_rn(xp[e * H_ * W_]);
        *(float4*)(xt + (size_t)t * 8) = pk.v;
    } else {
        int t = (blockIdx.x - 2048) * 256 + tid;  // (ch,g,o), 6144 total
        if (t >= NCHUNK * NGW * O_) return;
        int o  = t & 63;
        int g  = (t >> 6) % NGW;
        int ch = (t >> 6) / NGW;
        union { __half h[8]; float4 v; } pk;
#pragma unroll
        for (int e = 0; e < 8; ++e)
            pk.h[e] = (g < 9) ? __float2half_rn(w[(o * C_ + ch * 8 + e) * 9 + g])
                              : __half(0.0f);
        *(float4*)(wt + (size_t)t * 8) = pk.v;
    }
}

__global__ __launch_bounds__(256, 4)
void dcn_mfma(const __half* __restrict__ xt, const float* __restrict__ off,
              const __half* __restrict__ wt, const float* __restrict__ bias,
              float* __restrict__ out) {
    __shared__ __align__(16) _Float16 sS[2 * SBUF];   // 20 KB double-buffered
    __shared__ __align__(16) _Float16 sT[TSLOTS * 8]; // 12 KB x-window tile

    const int tid = threadIdx.x;
    const int bid = blockIdx.x;              // (b, ho-pair, wo-quarter)
    const int w4  = bid & 3;
    const int hp  = (bid >> 2) & 63;
    const int b   = bid >> 8;
    const int ho  = hp << 1;                 // rows ho, ho+1
    const int woB = w4 * NT_;
    const int yb  = ho - 6;                  // tile origin (row)
    const int xb  = woB - 8;                 // tile origin (col)

    // ---- bilinear metadata per task (k, row, wo_local): precomputed slot
    // addresses (tile-local if in-window, global if fallback) + fp16 weights ----
    // round r<2: task = tid + r*256 (all lanes); round 2: 64 tasks spread
    // across all 4 waves (lanes with tid%4==0) to avoid a single-wave straggler.
    int a0_[3], a1_[3], nf_[3];
    __half2 ua2_[3], ub2_[3], va2_[3], vb2_[3];
#pragma unroll
    for (int r = 0; r < 3; ++r) {
        bool act = (r < 2) || ((tid & 3) == 0);
        if (act) {
            int task = (r < 2) ? (tid + r * 256) : (512 + (tid >> 2));
            int k  = task >> 6;              // tap 0..8
            int n  = task & 63;              // row*32 + wo_local
            int wo = (n & 31) + woB;
            int hr = ho + (n >> 5);
            int ki = k / 3, kj = k - 3 * ki;
            float oy = off[(((b * 18) + 2 * k    ) * HO_ + hr) * WO_ + wo];
            float ox = off[(((b * 18) + 2 * k + 1) * HO_ + hr) * WO_ + wo];
            float py = (float)(hr - 1 + ki) + oy;
            float px = (float)(wo - 1 + kj) + ox;
            float y0f = floorf(py), x0f = floorf(px);
            int   y0 = (int)y0f,   x0 = (int)x0f;
            float ly = py - y0f,   lx = px - x0f;
            float hy = 1.f - ly,   hx = 1.f - lx;
            int y1 = y0 + 1, x1 = x0 + 1;
            float vy0 = (y0 >= 0 && y0 < H_) ? 1.f : 0.f;
            float vy1 = (y1 >= 0 && y1 < H_) ? 1.f : 0.f;
            float vx0 = (x0 >= 0 && x0 < W_) ? 1.f : 0.f;
            float vx1 = (x1 >= 0 && x1 < W_) ? 1.f : 0.f;
            int cy0 = min(max(y0, 0), H_ - 1), cy1 = min(max(y1, 0), H_ - 1);
            int ax  = min(max(x0, 0), W_ - 2);
            int cx0 = min(max(x0, 0), W_ - 1), cx1 = min(max(x1, 0), W_ - 1);
            float w00 = hy * hx * vy0 * vx0;
            float w01 = hy * lx * vy0 * vx1;
            float w10 = ly * hx * vy1 * vx0;
            float w11 = ly * lx * vy1 * vx1;
            float s0 = (cx0 != ax) ? 1.f : 0.f;
            float s1 = (cx1 != ax) ? 1.f : 0.f;
            int t0 = cy0 - yb, t1 = cy1 - yb, txx = ax - xb;
            int fb = ((unsigned)t0  > (TR - 1)) |
                     ((unsigned)t1  > (TR - 1)) |
                     ((unsigned)txx > (TC - 2));
            nf_[r] = !fb;
            a0_[r] = fb ? (cy0 * W_ + ax) : (t0 * TC + txx);
            a1_[r] = fb ? (cy1 * W_ + ax) : (t1 * TC + txx);
            ua2_[r] = __float2half2_rn(w00 * (1.f - s0) + w01 * (1.f - s1));
            ub2_[r] = __float2half2_rn(w00 * s0 + w01 * s1);
            va2_[r] = __float2half2_rn(w10 * (1.f - s0) + w11 * (1.f - s1));
            vb2_[r] = __float2half2_rn(w10 * s0 + w11 * s1);
        }
    }

    // ---- stage-slot global offsets (clamped), 3 slots/thread (768 = 3*256) ----
    int gofs[3];
#pragma unroll
    for (int j = 0; j < 3; ++j) {
        int s  = tid + j * 256;
        int rr = s / TC, cc = s - rr * TC;
        int yc = min(max(yb + rr, 0), H_ - 1);
        int xc = min(max(xb + cc, 0), W_ - 1);
        gofs[j] = yc * W_ + xc;
    }

    // zero pad group (group 9) in both sS buffers: 256 dwords each
    ((unsigned int*)&sS[9 * NCOL * 8])[tid]        = 0u;
    ((unsigned int*)&sS[SBUF + 9 * NCOL * 8])[tid] = 0u;

    // ---- window prefetch registers ----
    float4 pf0, pf1, pf2;
    auto issue = [&](int ch) {
        const float4* xc = (const float4*)(xt + ((size_t)(b * NCHUNK + ch)) * (H_ * W_ * 8));
        pf0 = xc[gofs[0]];
        pf1 = xc[gofs[1]];
        pf2 = xc[gofs[2]];
    };

    // ---- sample: LDS-window bilinear gather + fp16 blend -> sS[parity] ----
    auto sample = [&](int ch) {
        _Float16* buf = sS + (ch & 1) * SBUF;
        const float4* xcg = (const float4*)(xt + ((size_t)(b * NCHUNK + ch)) * (H_ * W_ * 8));
        const float4* tl  = (const float4*)sT;
#pragma unroll
        for (int r = 0; r < 3; ++r) {
            bool act = (r < 2) || ((tid & 3) == 0);
            if (act) {
                int task = (r < 2) ? (tid + r * 256) : (512 + (tid >> 2));
                int k = task >> 6;
                int n = task & 63;
                int a0 = a0_[r], a1 = a1_[r];
                H8 q00, q01, q10, q11;
                if (nf_[r]) {
                    q00.v = tl[a0];  q01.v = tl[a0 + 1];
                    q10.v = tl[a1];  q11.v = tl[a1 + 1];
                } else {   // exact fallback for |offset| beyond the window (~never)
                    q00.v = xcg[a0]; q01.v = xcg[a0 + 1];
                    q10.v = xcg[a1]; q11.v = xcg[a1 + 1];
                }
                H8 s;
#pragma unroll
                for (int j = 0; j < 4; ++j) {
                    __half2 t0 = __hmul2(ua2_[r], q00.h2[j]);
                    t0 = __hfma2(ub2_[r], q01.h2[j], t0);
                    t0 = __hfma2(va2_[r], q10.h2[j], t0);
                    t0 = __hfma2(vb2_[r], q11.h2[j], t0);
                    s.h2[j] = t0;
                }
                *(half8*)&buf[(k * NCOL + n) * 8] = s.v8;
            }
        }
    };

    // ---- GEMM lane mapping: 2(o-half) x 2(n-half) wave split ----
    const int lane = tid & 63;
    const int wv   = tid >> 6;
    const int ow   = wv & 1;       // o half  (32)
    const int nw   = wv >> 1;      // n half  (32 = one ho row)
    const int quad = lane >> 4;
    const int l15  = lane & 15;

    f32x4 acc[2][2];
#pragma unroll
    for (int ot = 0; ot < 2; ++ot)
#pragma unroll
        for (int nt = 0; nt < 2; ++nt)
            acc[ot][nt] = (f32x4){0.f, 0.f, 0.f, 0.f};

    auto mfma_chunk = [&](int ch) {
        const __half*   wc  = wt + (size_t)(ch * NGW) * O_ * 8;
        const _Float16* buf = sS + (ch & 1) * SBUF;
#pragma unroll
        for (int ks = 0; ks < KSTEPS; ++ks) {
            int g  = ks * 4 + quad;
            int gb = (g < 9) ? g : 9;            // groups 9..11 -> zero pad
            half8 bfr0 = *(const half8*)&buf[(gb * NCOL + nw * 32 +      l15) * 8];
            half8 bfr1 = *(const half8*)&buf[(gb * NCOL + nw * 32 + 16 + l15) * 8];
#pragma unroll
            for (int ot = 0; ot < 2; ++ot) {
                half8 afr = *(const half8*)(wc + (size_t)(g * O_ + ow * 32 + ot * 16 + l15) * 8);
                acc[ot][0] = __builtin_amdgcn_mfma_f32_16x16x32_f16(afr, bfr0, acc[ot][0], 0, 0, 0);
                acc[ot][1] = __builtin_amdgcn_mfma_f32_16x16x32_f16(afr, bfr1, acc[ot][1], 0, 0, 0);
            }
        }
    };

    issue(0);
    for (int ch = 0; ch < NCHUNK; ++ch) {
        // write the x-window tile (waits on the prefetch issued last chunk)
        float4* tw = (float4*)sT;
        tw[tid]       = pf0;
        tw[tid + 256] = pf1;
        tw[tid + 512] = pf2;
        __syncthreads();                       // tile ready; sS[(ch-1)&1] complete
        if (ch + 1 < NCHUNK) issue(ch + 1);    // overlap next window fetch with compute
        sample(ch);                            // LDS gather -> sS[ch&1]
        if (ch > 0) mfma_chunk(ch - 1);        // reads sS[(ch-1)&1], other parity
        __syncthreads();                       // sample done: tile free, sS[ch&1] ready
    }
    mfma_chunk(NCHUNK - 1);

    // ---- epilogue: C/D col = lane&15 (n), row = quad*4+reg (o) ----
#pragma unroll
    for (int ot = 0; ot < 2; ++ot) {
#pragma unroll
        for (int nt = 0; nt < 2; ++nt) {
            int n   = nw * 32 + nt * 16 + l15;
            int row = n >> 5;
            int wo  = woB + (n & 31);
#pragma unroll
            for (int rg = 0; rg < 4; ++rg) {
                int o = ow * 32 + ot * 16 + quad * 4 + rg;
                out[(((size_t)(b * O_ + o)) * HO_ + ho + row) * WO_ + wo] =
                    acc[ot][nt][rg] + bias[o];
            }
        }
    }
}

extern "C" void kernel_launch(void* const* d_in, const int* in_sizes, int n_in,
                              void* d_out, int out_size, void* d_ws, size_t ws_size,
                              hipStream_t stream) {
    const float* x    = (const float*)d_in[0];
    const float* off  = (const float*)d_in[1];
    const float* w    = (const float*)d_in[2];
    const float* bias = (const float*)d_in[3];
    float* out = (float*)d_out;

    __half* wt = (__half*)d_ws;                       // 98304 B
    __half* xt = (__half*)((char*)d_ws + 262144);     // 8 MB

    hipLaunchKernelGGL(prep, dim3(2048 + 24), dim3(256), 0, stream, x, w, xt, wt);
    hipLaunchKernelGGL(dcn_mfma, dim3(B_ * (HO_ / NROW) * (WO_ / NT_)), dim3(256), 0, stream,
                       xt, off, wt, bias, out);
}